// Round 18
// baseline (691.967 us; speedup 1.0000x reference)
//
#include <hip/hip_runtime.h>
#include <hip/hip_bf16.h>

#define B_ 16
#define S_ 4096
#define DM_ 1280
#define DC_ 768
#define NC_ 384
#define SCALE_ 0.07905694150420949f

typedef __attribute__((ext_vector_type(8))) short bf16x8;
typedef __attribute__((ext_vector_type(4))) float f32x4;
typedef __attribute__((ext_vector_type(4))) unsigned short u16x4;

#define S_BARRIER() asm volatile("s_barrier" ::: "memory")
#define WAIT_VM(n) asm volatile("s_waitcnt vmcnt(" #n ")" ::: "memory")
#define WAIT_LGKM0() asm volatile("s_waitcnt lgkmcnt(0)" ::: "memory")

__device__ __forceinline__ unsigned short f2bf(float f) {
    unsigned int u = __builtin_bit_cast(unsigned int, f);
    u = (u + 0x7FFFu + ((u >> 16) & 1u)) >> 16;
    return (unsigned short)u;
}

__device__ __forceinline__ bf16x8 pack8(float4 x0, float4 x1) {
    bf16x8 a;
    a[0] = __builtin_bit_cast(short, __float2bfloat16(x0.x));
    a[1] = __builtin_bit_cast(short, __float2bfloat16(x0.y));
    a[2] = __builtin_bit_cast(short, __float2bfloat16(x0.z));
    a[3] = __builtin_bit_cast(short, __float2bfloat16(x0.w));
    a[4] = __builtin_bit_cast(short, __float2bfloat16(x1.x));
    a[5] = __builtin_bit_cast(short, __float2bfloat16(x1.y));
    a[6] = __builtin_bit_cast(short, __float2bfloat16(x1.z));
    a[7] = __builtin_bit_cast(short, __float2bfloat16(x1.w));
    return a;
}

__device__ __forceinline__ void gload16(const void* g, void* l) {
    __builtin_amdgcn_global_load_lds(
        (const __attribute__((address_space(1))) void*)g,
        (__attribute__((address_space(3))) void*)l, 16, 0, 0);
}

// ---------- merged prep: wq cvt + 5 transpose/cvt ----------
__device__ __forceinline__ void tcvt_body(const float* __restrict__ in,
                                          unsigned short* __restrict__ out,
                                          int R, int C, int bx, int by, int tid) {
    __shared__ float tile[32][33];
    int c0 = bx * 32, r0 = by * 32;
    int tx = tid & 31, ty = tid >> 5;
    for (int i = ty; i < 32; i += 8)
        tile[i][tx] = in[(size_t)(r0 + i) * C + c0 + tx];
    __syncthreads();
    for (int i = ty; i < 32; i += 8)
        out[(size_t)(c0 + i) * R + r0 + tx] = f2bf(tile[tx][i]);
}

__global__ __launch_bounds__(256)
void k_prep(const float* __restrict__ wq, const float* __restrict__ wk,
            const float* __restrict__ wv, const float* __restrict__ wkd,
            const float* __restrict__ wvd, const float* __restrict__ wout,
            unsigned short* __restrict__ wq_bf, unsigned short* __restrict__ wTk,
            unsigned short* __restrict__ wTv, unsigned short* __restrict__ wTkd,
            unsigned short* __restrict__ wTvd, unsigned short* __restrict__ woutT) {
    int bid = blockIdx.x, tid = threadIdx.x;
    if (bid < 1600) {
        int i = bid * 256 + tid;
        float4 v = ((const float4*)wq)[i];
        u16x4 o = { f2bf(v.x), f2bf(v.y), f2bf(v.z), f2bf(v.w) };
        ((u16x4*)wq_bf)[i] = o;
    } else if (bid < 2560) {
        int r = bid - 1600; tcvt_body(wk,  wTk,  DC_, DM_, r % 40, r / 40, tid);
    } else if (bid < 3520) {
        int r = bid - 2560; tcvt_body(wv,  wTv,  DC_, DM_, r % 40, r / 40, tid);
    } else if (bid < 4480) {
        int r = bid - 3520; tcvt_body(wkd, wTkd, DC_, DM_, r % 40, r / 40, tid);
    } else if (bid < 5440) {
        int r = bid - 4480; tcvt_body(wvd, wTvd, DC_, DM_, r % 40, r / 40, tid);
    } else {
        int r = bid - 5440; tcvt_body(wout, woutT, DM_, DM_, r % 40, r / 40, tid);
    }
}

// ---------- A/U build with folded projection ----------
// At2[b][40][384c][32d], Ut2[b][12][1280e][32c]
__global__ __launch_bounds__(256)
void k_au2(const float* __restrict__ enc,
           const unsigned short* __restrict__ wTk, const unsigned short* __restrict__ wTv,
           const unsigned short* __restrict__ wTkd, const unsigned short* __restrict__ wTvd,
           const unsigned short* __restrict__ wqbf, const unsigned short* __restrict__ woutT,
           unsigned short* __restrict__ At2, unsigned short* __restrict__ Ut2) {
    __shared__ unsigned short kvLds[16 * 168];
    int bid0 = blockIdx.x;
    bool isA = bid0 < 384;
    int bid = isA ? bid0 : bid0 - 384;
    int b = bid & 15, r_ = bid >> 4, x = r_ >> 3, h = r_ & 7;
    int tid = threadIdx.x, w = tid >> 6, l = tid & 63, l15 = l & 15, l4 = l >> 4;
    int xh = x * 8 + h;
    int tok0 = (x == 0) ? 16 : ((x == 1) ? 0 : 32);
    const unsigned short* wTproj = isA ? ((x == 0) ? wTk : wTkd)
                                       : ((x == 0) ? wTv : wTvd);
    const unsigned short* wmat = isA ? wqbf : woutT;
    float postscale = isA ? SCALE_ : ((x == 2) ? 1.0f : 0.5f);
    f32x4 zero = {0.f, 0.f, 0.f, 0.f};

    {
        const float* ap = enc + ((size_t)(b * 48 + tok0 + l15)) * DC_;
        f32x4 pacc[3];
        #pragma unroll
        for (int i = 0; i < 3; i++) pacc[i] = zero;
        for (int kk = 0; kk < 24; kk++) {
            const float4* hp = (const float4*)(ap + kk * 32 + l4 * 8);
            bf16x8 af = pack8(hp[0], hp[1]);
            int i = 0;
            for (int t2 = w; t2 < 10; t2 += 4, i++) {
                int n0 = h * 160 + t2 * 16;
                bf16x8 bf = *(const bf16x8*)(wTproj + (size_t)(n0 + l15) * DC_ + kk * 32 + l4 * 8);
                pacc[i] = __builtin_amdgcn_mfma_f32_16x16x32_bf16(af, bf, pacc[i], 0, 0, 0);
            }
        }
        int i = 0;
        for (int t2 = w; t2 < 10; t2 += 4, i++) {
            #pragma unroll
            for (int r = 0; r < 4; r++)
                kvLds[(l4 * 4 + r) * 168 + t2 * 16 + l15] = f2bf(pacc[i][r]);
        }
    }
    __syncthreads();

    bf16x8 bfr[5];
    #pragma unroll
    for (int kk = 0; kk < 5; kk++)
        bfr[kk] = *(const bf16x8*)&kvLds[l15 * 168 + kk * 32 + l4 * 8];

    for (int tt = 0; tt < 20; tt++) {
        int d0 = w * 320 + tt * 16;
        f32x4 acc = zero;
        if (isA) {
            #pragma unroll
            for (int kk = 0; kk < 5; kk++) {
                bf16x8 af = *(const bf16x8*)(wmat + (size_t)(d0 + l15) * DM_ + h * 160 + kk * 32 + l4 * 8);
                acc = __builtin_amdgcn_mfma_f32_16x16x32_bf16(af, bfr[kk], acc, 0, 0, 0);
            }
            int c = xh * 16 + l15;
            u16x4 pk;
            #pragma unroll
            for (int r = 0; r < 4; r++) pk[r] = f2bf(acc[r] * postscale);
            *(u16x4*)(At2 + ((size_t)(b * 40 + (d0 >> 5)) * NC_ + c) * 32 + (d0 & 31) + l4 * 4) = pk;
        } else {
            #pragma unroll
            for (int kk = 0; kk < 5; kk++) {
                bf16x8 af = *(const bf16x8*)(wmat + (size_t)(d0 + l15) * DM_ + h * 160 + kk * 32 + l4 * 8);
                acc = __builtin_amdgcn_mfma_f32_16x16x32_bf16(bfr[kk], af, acc, 0, 0, 0);
            }
            int e = d0 + l15;
            u16x4 pk;
            #pragma unroll
            for (int r = 0; r < 4; r++) pk[r] = f2bf(acc[r] * postscale);
            *(u16x4*)(Ut2 + ((size_t)(b * 12 + (xh >> 1)) * DM_ + e) * 32 + (xh & 1) * 16 + l4 * 4) = pk;
        }
    }
}

// ---------- FUSED v3: phase 1 barrier-free register-direct (L1-shared A); ----------
// ---------- P in registers; phase 2 = proven LDS-U structure             ----------
__global__ __launch_bounds__(256, 3)
void k_fused3(const float* __restrict__ hid, const unsigned short* __restrict__ At2,
              const unsigned short* __restrict__ Ut2, const float* __restrict__ bo,
              float* __restrict__ out) {
    __shared__ char smem[49152];                 // phase 2 only: U chunk 48KB
    int bid = blockIdx.x;
    int orig = (bid & 7) * 128 + (bid >> 3);     // XCD-chunked
    int b = orig >> 6, st = orig & 63;
    int s0 = st * 64;
    int tid = threadIdx.x, w = tid >> 6, l = tid & 63, l15 = l & 15, l4 = l >> 4;
    int rdsw = (l4 ^ ((l15 >> 1) & 3)) * 8;
    f32x4 zero = {0.f, 0.f, 0.f, 0.f};

    uint4 pf4[12];                               // P as 12 MFMA B-fragments

    // ===== phase 1: barrier-free scores; wave = 16 s x 384 c; A/H direct from global =====
    {
        f32x4 acc[24];
        #pragma unroll
        for (int g = 0; g < 24; g++) acc[g] = zero;

        // A fragment (g,kk): 1 KB contiguous; lane offset = l15*64B + l4*16B
        const unsigned short* Afr = At2 + (size_t)b * 40 * NC_ * 32 + l15 * 32 + l4 * 8;
        const float* hrow = hid + ((size_t)b * S_ + s0 + w * 16 + l15) * DM_ + l4 * 8;

        for (int kk = 0; kk < 40; kk++) {
            const float4* hp = (const float4*)(hrow + kk * 32);
            bf16x8 hpk = pack8(hp[0], hp[1]);
            const unsigned short* slab = Afr + (size_t)kk * (NC_ * 32);
            #pragma unroll
            for (int g = 0; g < 24; g++) {
                bf16x8 af = *(const bf16x8*)(slab + g * 512);
                acc[g] = __builtin_amdgcn_mfma_f32_16x16x32_bf16(af, hpk, acc[g], 0, 0, 0);
            }
        }

        // softmax per 16-c group + in-register B-fragment assembly (consumes acc per-K)
        int srcA = (((2 * l4) & 3) << 4) | l15;
        int srcB = (((2 * l4 + 1) & 3) << 4) | l15;
        bool hiG = (l4 >= 2);
        #pragma unroll
        for (int K = 0; K < 12; K++) {
            unsigned int Wg[2][2];
            #pragma unroll
            for (int t = 0; t < 2; t++) {
                f32x4 a = acc[2 * K + t];
                float v0 = a[0], v1 = a[1], v2 = a[2], v3 = a[3];
                float mx = fmaxf(fmaxf(v0, v1), fmaxf(v2, v3));
                mx = fmaxf(mx, __shfl_xor(mx, 16));
                mx = fmaxf(mx, __shfl_xor(mx, 32));
                float e0 = __expf(v0 - mx), e1 = __expf(v1 - mx), e2 = __expf(v2 - mx), e3 = __expf(v3 - mx);
                float sm = e0 + e1 + e2 + e3;
                sm += __shfl_xor(sm, 16);
                sm += __shfl_xor(sm, 32);
                float rs = 1.0f / sm;
                Wg[t][0] = (unsigned int)f2bf(e0 * rs) | ((unsigned int)f2bf(e1 * rs) << 16);
                Wg[t][1] = (unsigned int)f2bf(e2 * rs) | ((unsigned int)f2bf(e3 * rs) << 16);
            }
            unsigned int a0 = (unsigned int)__shfl((int)Wg[0][0], srcA);
            unsigned int a1 = (unsigned int)__shfl((int)Wg[0][1], srcA);
            unsigned int b0 = (unsigned int)__shfl((int)Wg[0][0], srcB);
            unsigned int b1 = (unsigned int)__shfl((int)Wg[0][1], srcB);
            unsigned int c0 = (unsigned int)__shfl((int)Wg[1][0], srcA);
            unsigned int c1 = (unsigned int)__shfl((int)Wg[1][1], srcA);
            unsigned int d0 = (unsigned int)__shfl((int)Wg[1][0], srcB);
            unsigned int d1 = (unsigned int)__shfl((int)Wg[1][1], srcB);
            uint4 fr;
            fr.x = hiG ? c0 : a0;
            fr.y = hiG ? c1 : a1;
            fr.z = hiG ? d0 : b0;
            fr.w = hiG ? d1 : b1;
            pf4[K] = fr;
        }
    }

    // ===== phase 2: PV with register P; U chunk (64 e x 384 c = 48KB) per frame =====
    const unsigned short* Ub = Ut2 + (size_t)b * 12 * DM_ * 32;
    unsigned short* Usm = (unsigned short*)smem;
    int srow = s0 + w * 16 + l15;

    for (int ecb = 0; ecb < 20; ecb++) {
        #pragma unroll
        for (int kk2 = 0; kk2 < 12; kk2++) {
            const unsigned short* slab = Ub + ((size_t)kk2 * DM_ + ecb * 64) * 32;
            int r = tid >> 2, m = (tid & 3) ^ ((r >> 1) & 3);
            gload16(slab + (size_t)r * 32 + m * 8, smem + kk2 * 4096 + tid * 16);
        }
        WAIT_VM(0);
        S_BARRIER();

        f32x4 acc2[4];
        #pragma unroll
        for (int ej = 0; ej < 4; ej++) acc2[ej] = zero;
        __builtin_amdgcn_s_setprio(1);
        #pragma unroll
        for (int kk2 = 0; kk2 < 12; kk2++) {
            bf16x8 pfr = __builtin_bit_cast(bf16x8, pf4[kk2]);
            #pragma unroll
            for (int ej = 0; ej < 4; ej++) {
                bf16x8 uf = *(const bf16x8*)&Usm[kk2 * 2048 + (ej * 16 + l15) * 32 + rdsw];
                acc2[ej] = __builtin_amdgcn_mfma_f32_16x16x32_bf16(uf, pfr, acc2[ej], 0, 0, 0);
            }
        }
        __builtin_amdgcn_s_setprio(0);
        WAIT_LGKM0();
        S_BARRIER();

        #pragma unroll
        for (int ej = 0; ej < 4; ej++) {
            int e0c = ecb * 64 + ej * 16 + l4 * 4;
            float4 b4 = *(const float4*)(bo + e0c);
            size_t off = ((size_t)b * S_ + srow) * DM_ + e0c;
            float4 h4 = *(const float4*)(hid + off);
            f32x4 a = acc2[ej];
            float4 o4;
            o4.x = a[0] + b4.x + h4.x;
            o4.y = a[1] + b4.y + h4.y;
            o4.z = a[2] + b4.z + h4.z;
            o4.w = a[3] + b4.w + h4.w;
            *(float4*)(out + off) = o4;
        }
    }
}

extern "C" void kernel_launch(void* const* d_in, const int* in_sizes, int n_in,
                              void* d_out, int out_size, void* d_ws, size_t ws_size,
                              hipStream_t stream) {
    const float* hid  = (const float*)d_in[0];
    const float* enc  = (const float*)d_in[1];
    const float* wq   = (const float*)d_in[2];
    const float* wk   = (const float*)d_in[3];
    const float* wv   = (const float*)d_in[4];
    const float* wkd  = (const float*)d_in[5];
    const float* wvd  = (const float*)d_in[6];
    const float* wout = (const float*)d_in[7];
    const float* bo   = (const float*)d_in[8];
    float* out = (float*)d_out;

    char* ws = (char*)d_ws;
    unsigned short* At2    = (unsigned short*)(ws);               // 15,728,640
    unsigned short* Ut2    = (unsigned short*)(ws + 15728640);    // 15,728,640
    unsigned short* wq_bf  = (unsigned short*)(ws + 31457280);    //  3,276,800
    unsigned short* woutT  = (unsigned short*)(ws + 34734080);    //  3,276,800
    unsigned short* wTk    = (unsigned short*)(ws + 38010880);    //  1,966,080
    unsigned short* wTv    = (unsigned short*)(ws + 39976960);    //  1,966,080
    unsigned short* wTkd   = (unsigned short*)(ws + 41943040);    //  1,966,080
    unsigned short* wTvd   = (unsigned short*)(ws + 43909120);    //  1,966,080 (end 45,875,200)

    k_prep<<<7040, 256, 0, stream>>>(wq, wk, wv, wkd, wvd, wout,
                                     wq_bf, wTk, wTv, wTkd, wTvd, woutT);
    k_au2<<<768, 256, 0, stream>>>(enc, wTk, wTv, wTkd, wTvd, wq_bf, woutT, At2, Ut2);
    k_fused3<<<1024, 256, 0, stream>>>(hid, At2, Ut2, bo, out);
}

// Round 19
// 388.005 us; speedup vs baseline: 1.7834x; 1.7834x over previous
//
#include <hip/hip_runtime.h>
#include <hip/hip_bf16.h>

#define B_ 16
#define S_ 4096
#define DM_ 1280
#define DC_ 768
#define NC_ 384
#define SCALE_ 0.07905694150420949f

typedef __attribute__((ext_vector_type(8))) short bf16x8;
typedef __attribute__((ext_vector_type(4))) float f32x4;
typedef __attribute__((ext_vector_type(4))) unsigned short u16x4;

#define S_BARRIER() asm volatile("s_barrier" ::: "memory")
#define WAIT_VM(n) asm volatile("s_waitcnt vmcnt(" #n ")" ::: "memory")
#define WAIT_LGKM0() asm volatile("s_waitcnt lgkmcnt(0)" ::: "memory")

__device__ __forceinline__ unsigned short f2bf(float f) {
    unsigned int u = __builtin_bit_cast(unsigned int, f);
    u = (u + 0x7FFFu + ((u >> 16) & 1u)) >> 16;
    return (unsigned short)u;
}

__device__ __forceinline__ bf16x8 pack8(float4 x0, float4 x1) {
    bf16x8 a;
    a[0] = __builtin_bit_cast(short, __float2bfloat16(x0.x));
    a[1] = __builtin_bit_cast(short, __float2bfloat16(x0.y));
    a[2] = __builtin_bit_cast(short, __float2bfloat16(x0.z));
    a[3] = __builtin_bit_cast(short, __float2bfloat16(x0.w));
    a[4] = __builtin_bit_cast(short, __float2bfloat16(x1.x));
    a[5] = __builtin_bit_cast(short, __float2bfloat16(x1.y));
    a[6] = __builtin_bit_cast(short, __float2bfloat16(x1.z));
    a[7] = __builtin_bit_cast(short, __float2bfloat16(x1.w));
    return a;
}

__device__ __forceinline__ void gload16(const void* g, void* l) {
    __builtin_amdgcn_global_load_lds(
        (const __attribute__((address_space(1))) void*)g,
        (__attribute__((address_space(3))) void*)l, 16, 0, 0);
}

// ---------- merged prep: wq cvt + 5 transpose/cvt ----------
__device__ __forceinline__ void tcvt_body(const float* __restrict__ in,
                                          unsigned short* __restrict__ out,
                                          int R, int C, int bx, int by, int tid) {
    __shared__ float tile[32][33];
    int c0 = bx * 32, r0 = by * 32;
    int tx = tid & 31, ty = tid >> 5;
    for (int i = ty; i < 32; i += 8)
        tile[i][tx] = in[(size_t)(r0 + i) * C + c0 + tx];
    __syncthreads();
    for (int i = ty; i < 32; i += 8)
        out[(size_t)(c0 + i) * R + r0 + tx] = f2bf(tile[tx][i]);
}

__global__ __launch_bounds__(256)
void k_prep(const float* __restrict__ wq, const float* __restrict__ wk,
            const float* __restrict__ wv, const float* __restrict__ wkd,
            const float* __restrict__ wvd, const float* __restrict__ wout,
            unsigned short* __restrict__ wq_bf, unsigned short* __restrict__ wTk,
            unsigned short* __restrict__ wTv, unsigned short* __restrict__ wTkd,
            unsigned short* __restrict__ wTvd, unsigned short* __restrict__ woutT) {
    int bid = blockIdx.x, tid = threadIdx.x;
    if (bid < 1600) {
        int i = bid * 256 + tid;
        float4 v = ((const float4*)wq)[i];
        u16x4 o = { f2bf(v.x), f2bf(v.y), f2bf(v.z), f2bf(v.w) };
        ((u16x4*)wq_bf)[i] = o;
    } else if (bid < 2560) {
        int r = bid - 1600; tcvt_body(wk,  wTk,  DC_, DM_, r % 40, r / 40, tid);
    } else if (bid < 3520) {
        int r = bid - 2560; tcvt_body(wv,  wTv,  DC_, DM_, r % 40, r / 40, tid);
    } else if (bid < 4480) {
        int r = bid - 3520; tcvt_body(wkd, wTkd, DC_, DM_, r % 40, r / 40, tid);
    } else if (bid < 5440) {
        int r = bid - 4480; tcvt_body(wvd, wTvd, DC_, DM_, r % 40, r / 40, tid);
    } else {
        int r = bid - 5440; tcvt_body(wout, woutT, DM_, DM_, r % 40, r / 40, tid);
    }
}

// ---------- A/U build with folded projection ----------
// At2[b][40][384c][32d], Ut2[b][12][1280e][32c]
__global__ __launch_bounds__(256)
void k_au2(const float* __restrict__ enc,
           const unsigned short* __restrict__ wTk, const unsigned short* __restrict__ wTv,
           const unsigned short* __restrict__ wTkd, const unsigned short* __restrict__ wTvd,
           const unsigned short* __restrict__ wqbf, const unsigned short* __restrict__ woutT,
           unsigned short* __restrict__ At2, unsigned short* __restrict__ Ut2) {
    __shared__ unsigned short kvLds[16 * 168];
    int bid0 = blockIdx.x;
    bool isA = bid0 < 384;
    int bid = isA ? bid0 : bid0 - 384;
    int b = bid & 15, r_ = bid >> 4, x = r_ >> 3, h = r_ & 7;
    int tid = threadIdx.x, w = tid >> 6, l = tid & 63, l15 = l & 15, l4 = l >> 4;
    int xh = x * 8 + h;
    int tok0 = (x == 0) ? 16 : ((x == 1) ? 0 : 32);
    const unsigned short* wTproj = isA ? ((x == 0) ? wTk : wTkd)
                                       : ((x == 0) ? wTv : wTvd);
    const unsigned short* wmat = isA ? wqbf : woutT;
    float postscale = isA ? SCALE_ : ((x == 2) ? 1.0f : 0.5f);
    f32x4 zero = {0.f, 0.f, 0.f, 0.f};

    {
        const float* ap = enc + ((size_t)(b * 48 + tok0 + l15)) * DC_;
        f32x4 pacc[3];
        #pragma unroll
        for (int i = 0; i < 3; i++) pacc[i] = zero;
        for (int kk = 0; kk < 24; kk++) {
            const float4* hp = (const float4*)(ap + kk * 32 + l4 * 8);
            bf16x8 af = pack8(hp[0], hp[1]);
            int i = 0;
            for (int t2 = w; t2 < 10; t2 += 4, i++) {
                int n0 = h * 160 + t2 * 16;
                bf16x8 bf = *(const bf16x8*)(wTproj + (size_t)(n0 + l15) * DC_ + kk * 32 + l4 * 8);
                pacc[i] = __builtin_amdgcn_mfma_f32_16x16x32_bf16(af, bf, pacc[i], 0, 0, 0);
            }
        }
        int i = 0;
        for (int t2 = w; t2 < 10; t2 += 4, i++) {
            #pragma unroll
            for (int r = 0; r < 4; r++)
                kvLds[(l4 * 4 + r) * 168 + t2 * 16 + l15] = f2bf(pacc[i][r]);
        }
    }
    __syncthreads();

    bf16x8 bfr[5];
    #pragma unroll
    for (int kk = 0; kk < 5; kk++)
        bfr[kk] = *(const bf16x8*)&kvLds[l15 * 168 + kk * 32 + l4 * 8];

    for (int tt = 0; tt < 20; tt++) {
        int d0 = w * 320 + tt * 16;
        f32x4 acc = zero;
        if (isA) {
            #pragma unroll
            for (int kk = 0; kk < 5; kk++) {
                bf16x8 af = *(const bf16x8*)(wmat + (size_t)(d0 + l15) * DM_ + h * 160 + kk * 32 + l4 * 8);
                acc = __builtin_amdgcn_mfma_f32_16x16x32_bf16(af, bfr[kk], acc, 0, 0, 0);
            }
            int c = xh * 16 + l15;
            u16x4 pk;
            #pragma unroll
            for (int r = 0; r < 4; r++) pk[r] = f2bf(acc[r] * postscale);
            *(u16x4*)(At2 + ((size_t)(b * 40 + (d0 >> 5)) * NC_ + c) * 32 + (d0 & 31) + l4 * 4) = pk;
        } else {
            #pragma unroll
            for (int kk = 0; kk < 5; kk++) {
                bf16x8 af = *(const bf16x8*)(wmat + (size_t)(d0 + l15) * DM_ + h * 160 + kk * 32 + l4 * 8);
                acc = __builtin_amdgcn_mfma_f32_16x16x32_bf16(bfr[kk], af, acc, 0, 0, 0);
            }
            int e = d0 + l15;
            u16x4 pk;
            #pragma unroll
            for (int r = 0; r < 4; r++) pk[r] = f2bf(acc[r] * postscale);
            *(u16x4*)(Ut2 + ((size_t)(b * 12 + (xh >> 1)) * DM_ + e) * 32 + (xh & 1) * 16 + l4 * 4) = pk;
        }
    }
}

// ---------- FUSED: scores -> softmax -> P in LDS -> barrier-free PV + epilogue ----------
__global__ __launch_bounds__(256, 2)
void k_fused(const float* __restrict__ hid, const unsigned short* __restrict__ At2,
             const unsigned short* __restrict__ Ut2, const float* __restrict__ bo,
             float* __restrict__ out) {
    __shared__ char smem[81920];                 // ph1: A 2x24KB @0, H 3x8KB @48K
                                                 // ph2: P 48KB @0,   U 4 waves x 2 x 4KB @48K
    unsigned short* Apnl = (unsigned short*)smem;
    char* Hlds = smem + 49152;
    int bid = blockIdx.x;
    int orig = (bid & 7) * 128 + (bid >> 3);     // XCD-chunked
    int b = orig >> 6, st = orig & 63;
    int s0 = st * 64;
    int tid = threadIdx.x, w = tid >> 6, l = tid & 63, l15 = l & 15, l4 = l >> 4;
    int rdsw = (l4 ^ ((l15 >> 1) & 3)) * 8;
    const unsigned short* Ab = At2 + (size_t)b * 40 * NC_ * 32;
    const float* hsrc = hid + ((size_t)b * S_ + s0) * DM_;
    f32x4 zero = {0.f, 0.f, 0.f, 0.f};

    // ===== phase 1: scores (R11-proven structure, barriers required: A is block-shared) =====
    {
        f32x4 acc[4][6];
        #pragma unroll
        for (int si = 0; si < 4; si++)
            #pragma unroll
            for (int cj = 0; cj < 6; cj++) acc[si][cj] = zero;

        auto stageA = [&](int kk, int ab) {
            const unsigned short* slab = Ab + (size_t)kk * (NC_ * 32);
            #pragma unroll
            for (int i = 0; i < 6; i++) {
                int idx = i * 256 + tid;
                int c = idx >> 2, m = (idx & 3) ^ ((c >> 1) & 3);
                gload16(slab + (size_t)c * 32 + m * 8, smem + ab * 24576 + idx * 16);
            }
        };
        auto stageH = [&](int kk, int hb) {
            #pragma unroll
            for (int i = 0; i < 2; i++) {
                int idx = i * 256 + tid;
                int r = idx >> 3, sg = (idx & 7) ^ (r & 7);
                gload16(hsrc + (size_t)r * DM_ + kk * 32 + sg * 4, Hlds + hb * 8192 + idx * 16);
            }
        };
        auto compute = [&](int ab, int hb) {
            bf16x8 hpk[4];
            #pragma unroll
            for (int si = 0; si < 4; si++) {
                int r = si * 16 + l15;
                float4 lo = *(const float4*)(Hlds + hb * 8192 + r * 128 + (((2 * l4) ^ (l15 & 7)) * 16));
                float4 hi = *(const float4*)(Hlds + hb * 8192 + r * 128 + (((2 * l4 + 1) ^ (l15 & 7)) * 16));
                hpk[si] = pack8(lo, hi);
            }
            __builtin_amdgcn_s_setprio(1);
            #pragma unroll
            for (int cj = 0; cj < 6; cj++) {
                bf16x8 af = *(const bf16x8*)&Apnl[ab * 12288 + (w * 96 + cj * 16 + l15) * 32 + rdsw];
                #pragma unroll
                for (int si = 0; si < 4; si++)
                    acc[si][cj] = __builtin_amdgcn_mfma_f32_16x16x32_bf16(af, hpk[si], acc[si][cj], 0, 0, 0);
            }
            __builtin_amdgcn_s_setprio(0);
        };
        auto SITER = [&](int kk) {
            stageA(kk + 1, (kk + 1) & 1);
            stageH(kk + 2, (kk + 2) % 3);
            WAIT_VM(10);
            S_BARRIER();
            compute(kk & 1, kk % 3);
            WAIT_LGKM0();
            S_BARRIER();
        };

        stageA(0, 0); stageH(0, 0); stageH(1, 1);
        for (int k0 = 0; k0 < 36; k0 += 6) {
            SITER(k0 + 0); SITER(k0 + 1); SITER(k0 + 2);
            SITER(k0 + 3); SITER(k0 + 4); SITER(k0 + 5);
        }
        SITER(36); SITER(37);
        stageA(39, 1);
        WAIT_VM(8);
        S_BARRIER();
        compute(0, 38 % 3);
        WAIT_LGKM0();
        S_BARRIER();
        WAIT_VM(0);
        S_BARRIER();
        compute(1, 39 % 3);
        WAIT_LGKM0();
        S_BARRIER();

        // softmax per 16-c group; P into LDS [kk2][64 s][32 c], chunk key q ^ ((s>>1)&3)
        #pragma unroll
        for (int si = 0; si < 4; si++) {
            int s_l = si * 16 + l15;
            #pragma unroll
            for (int cj = 0; cj < 6; cj++) {
                float v0 = acc[si][cj][0], v1 = acc[si][cj][1], v2 = acc[si][cj][2], v3 = acc[si][cj][3];
                float mx = fmaxf(fmaxf(v0, v1), fmaxf(v2, v3));
                mx = fmaxf(mx, __shfl_xor(mx, 16));
                mx = fmaxf(mx, __shfl_xor(mx, 32));
                float e0 = __expf(v0 - mx), e1 = __expf(v1 - mx), e2 = __expf(v2 - mx), e3 = __expf(v3 - mx);
                float sm = e0 + e1 + e2 + e3;
                sm += __shfl_xor(sm, 16);
                sm += __shfl_xor(sm, 32);
                float rs = 1.0f / sm;
                u16x4 pk = { f2bf(e0 * rs), f2bf(e1 * rs), f2bf(e2 * rs), f2bf(e3 * rs) };
                int c = w * 96 + cj * 16 + l4 * 4;
                int chunk = ((c & 31) >> 3) ^ ((s_l >> 1) & 3);
                *(u16x4*)(smem + (c >> 5) * 4096 + s_l * 64 + chunk * 16 + (l4 & 1) * 8) = pk;
            }
        }
    }
    __syncthreads();   // P visible to all waves; no further cross-wave LDS deps

    // ===== phase 2: BARRIER-FREE PV; wave-private U staging, per-wave counted vmcnt =====
    const unsigned short* Ub = Ut2 + (size_t)b * 12 * DM_ * 32;
    unsigned short* UldsW = (unsigned short*)(smem + 49152 + w * 8192);  // 2 x 4KB per wave

    auto stageU = [&](int kk2, int ec, int buf) {   // 4 gload_lds, wave's own 64-e slice
        const unsigned short* slab = Ub + ((size_t)kk2 * DM_ + ec * 256 + w * 64) * 32;
        #pragma unroll
        for (int i = 0; i < 4; i++) {
            int idx = i * 64 + l;
            int r = idx >> 2, m = (idx & 3) ^ ((r >> 1) & 3);
            gload16(slab + (size_t)r * 32 + m * 8, (char*)UldsW + buf * 4096 + idx * 16);
        }
    };

    for (int ec = 0; ec < 5; ec++) {
        f32x4 accp[4][4];
        #pragma unroll
        for (int si = 0; si < 4; si++)
            #pragma unroll
            for (int ej = 0; ej < 4; ej++) accp[si][ej] = zero;

        stageU(0, ec, 0);
        for (int kk2 = 0; kk2 < 12; kk2++) {
            if (kk2 < 11) {
                stageU(kk2 + 1, ec, (kk2 + 1) & 1);
                WAIT_VM(4);                      // per-wave: drain stage kk2, keep kk2+1 in flight
            } else {
                WAIT_VM(0);
            }
            int buf = kk2 & 1;
            bf16x8 uf[4], pf[4];
            #pragma unroll
            for (int ej = 0; ej < 4; ej++)
                uf[ej] = *(const bf16x8*)&UldsW[buf * 2048 + (ej * 16 + l15) * 32 + rdsw];
            #pragma unroll
            for (int si = 0; si < 4; si++) {
                int s_l = si * 16 + l15;
                pf[si] = *(const bf16x8*)(smem + kk2 * 4096 + s_l * 64 + ((l4 ^ ((s_l >> 1) & 3)) * 16));
            }
            __builtin_amdgcn_s_setprio(1);
            #pragma unroll
            for (int si = 0; si < 4; si++)
                #pragma unroll
                for (int ej = 0; ej < 4; ej++)
                    accp[si][ej] = __builtin_amdgcn_mfma_f32_16x16x32_bf16(uf[ej], pf[si], accp[si][ej], 0, 0, 0);
            __builtin_amdgcn_s_setprio(0);
        }

        // epilogue (register loads/stores; wave-local e-range)
        #pragma unroll
        for (int ej = 0; ej < 4; ej++) {
            int e0c = ec * 256 + w * 64 + ej * 16 + l4 * 4;
            float4 b4 = *(const float4*)(bo + e0c);
            #pragma unroll
            for (int si = 0; si < 4; si++) {
                int srow = s0 + si * 16 + l15;
                size_t off = ((size_t)b * S_ + srow) * DM_ + e0c;
                float4 h4 = *(const float4*)(hid + off);
                f32x4 a = accp[si][ej];
                float4 o4;
                o4.x = a[0] + b4.x + h4.x;
                o4.y = a[1] + b4.y + h4.y;
                o4.z = a[2] + b4.z + h4.z;
                o4.w = a[3] + b4.w + h4.w;
                *(float4*)(out + off) = o4;
            }
        }
        WAIT_VM(0);   // drain epilogue register loads/stores before next ec's counted stream
    }
}

extern "C" void kernel_launch(void* const* d_in, const int* in_sizes, int n_in,
                              void* d_out, int out_size, void* d_ws, size_t ws_size,
                              hipStream_t stream) {
    const float* hid  = (const float*)d_in[0];
    const float* enc  = (const float*)d_in[1];
    const float* wq   = (const float*)d_in[2];
    const float* wk   = (const float*)d_in[3];
    const float* wv   = (const float*)d_in[4];
    const float* wkd  = (const float*)d_in[5];
    const float* wvd  = (const float*)d_in[6];
    const float* wout = (const float*)d_in[7];
    const float* bo   = (const float*)d_in[8];
    float* out = (float*)d_out;

    char* ws = (char*)d_ws;
    unsigned short* At2    = (unsigned short*)(ws);               // 15,728,640
    unsigned short* Ut2    = (unsigned short*)(ws + 15728640);    // 15,728,640
    unsigned short* wq_bf  = (unsigned short*)(ws + 31457280);    //  3,276,800
    unsigned short* woutT  = (unsigned short*)(ws + 34734080);    //  3,276,800
    unsigned short* wTk    = (unsigned short*)(ws + 38010880);    //  1,966,080
    unsigned short* wTv    = (unsigned short*)(ws + 39976960);    //  1,966,080
    unsigned short* wTkd   = (unsigned short*)(ws + 41943040);    //  1,966,080
    unsigned short* wTvd   = (unsigned short*)(ws + 43909120);    //  1,966,080 (end 45,875,200)

    k_prep<<<7040, 256, 0, stream>>>(wq, wk, wv, wkd, wvd, wout,
                                     wq_bf, wTk, wTv, wTkd, wTvd, woutT);
    k_au2<<<768, 256, 0, stream>>>(enc, wTk, wTv, wTkd, wTvd, wq_bf, woutT, At2, Ut2);
    k_fused<<<1024, 256, 0, stream>>>(hid, At2, Ut2, bo, out);
}